// Round 9
// baseline (186.830 us; speedup 1.0000x reference)
//
#include <hip/hip_runtime.h>
#include <cstdint>

#define N_TOK 4096
#define DMODEL 512
#define NHEADS 8
#define HDIM 64

typedef unsigned short u16;
typedef __bf16 bf16x8 __attribute__((ext_vector_type(8)));
typedef float f32x4 __attribute__((ext_vector_type(4)));

union U128 { uint4 u; bf16x8 b; u16 s[8]; };

__device__ __forceinline__ u16 f2bf(float f) {           // RNE
  uint32_t u = __builtin_bit_cast(uint32_t, f);
  u += 0x7FFFu + ((u >> 16) & 1u);
  return (u16)(u >> 16);
}
__device__ __forceinline__ float bf2f(u16 s) {
  uint32_t u = ((uint32_t)s) << 16;
  return __builtin_bit_cast(float, u);
}

#if __has_builtin(__builtin_amdgcn_exp2f)
#define EXP2(x) __builtin_amdgcn_exp2f(x)
#else
#define EXP2(x) __expf((x) * 0.6931471805599453f)
#endif

// v_cvt_pk_bf16_f32: packs two f32 into one u32 of 2 bf16 (RNE), src0 -> lo.
// Same bits as f2bf (both RNE).
__device__ __forceinline__ uint32_t cvtpk(float lo, float hi) {
  uint32_t r;
  asm("v_cvt_pk_bf16_f32 %0, %1, %2" : "=v"(r) : "v"(lo), "v"(hi));
  return r;
}
__device__ __forceinline__ uint4 pack8(const float4& a, const float4& b) {
  uint4 p;
  p.x = cvtpk(a.x, a.y); p.y = cvtpk(a.z, a.w);
  p.z = cvtpk(b.x, b.y); p.w = cvtpk(b.z, b.w);
  return p;
}

// async global->LDS, 16B/lane, dest = wave-uniform base + lane*16
__device__ __forceinline__ void ldg2lds16(const void* g, void* s) {
  __builtin_amdgcn_global_load_lds(
      (const __attribute__((address_space(1))) void*)g,
      (__attribute__((address_space(3))) void*)s, 16, 0, 0);
}

// ---------------------------------------------------------------------------
// Kernel 1 (r19): fused QKV projection reading fp32 DIRECTLY (cvt7 deleted).
// Staging = async-STAGE split (G15/T14): global_load fp32 -> [MFMA compute]
// -> cvt_pk + ds_write_b128 -> barrier.  LDS layout, fragment reads, MFMA
// order, and epilogue are byte-identical to r18; cvt_pk is RNE = same bits
// as the old cvt7 pass -> output bit-identical (absmax probe: 0.03125).
// 128x64 tile, m=2, double-buffered.  V branch writes V^T.
// grid (32, 8, 3), block 256.
// ---------------------------------------------------------------------------
__global__ __launch_bounds__(256) void proj3_kernel(
    const float* __restrict__ Qf, const float* __restrict__ Kf, const float* __restrict__ Vf,
    const float* __restrict__ WQ, const float* __restrict__ WK, const float* __restrict__ WV,
    const float* __restrict__ bQ, const float* __restrict__ bK, const float* __restrict__ bV,
    u16* __restrict__ Qs, u16* __restrict__ Ks, u16* __restrict__ Vt)
{
  const int z = blockIdx.z;
  const float* A    = (z == 0) ? Qf : (z == 1) ? Kf : Vf;
  const float* W    = (z == 0) ? WQ : (z == 1) ? WK : WV;
  const float* bias = (z == 0) ? bQ : (z == 1) ? bK : bV;

  const int m0 = blockIdx.x * 128;
  const int j0 = blockIdx.y * 64;
  const int tid = threadIdx.x;
  const int w = tid >> 6, lane = tid & 63, quad = lane >> 4, l = lane & 15;

  __shared__ bf16x8 sA[2][8][128];  // 32 KB
  __shared__ bf16x8 sB[2][8][64];   // 16 KB

  const f32x4 zero = {0.f, 0.f, 0.f, 0.f};
  f32x4 acc[2][4];
#pragma unroll
  for (int m = 0; m < 2; ++m)
#pragma unroll
    for (int s = 0; s < 4; ++s) acc[m][s] = zero;

  // reg-staged fp32 loads (statically indexed — rule #20)
  float4 fa[4][2], fb[2][2];

  auto stage_load = [&](int kt) {
    const int k0 = kt * 64;
#pragma unroll
    for (int i = 0; i < 4; ++i) {
      const int chunk = 2 * w + (i >> 1), half = (i & 1) * 64;
      const float* ag = A + (size_t)(m0 + half + lane) * DMODEL + k0 + chunk * 8;
      fa[i][0] = *(const float4*)ag;
      fa[i][1] = *(const float4*)(ag + 4);
    }
#pragma unroll
    for (int i = 0; i < 2; ++i) {
      const int chunk = 2 * w + i;
      const float* bg = W + (size_t)(j0 + lane) * DMODEL + k0 + chunk * 8;
      fb[i][0] = *(const float4*)bg;
      fb[i][1] = *(const float4*)(bg + 4);
    }
  };
  auto stage_write = [&](int buf) {
#pragma unroll
    for (int i = 0; i < 4; ++i) {
      const int chunk = 2 * w + (i >> 1), half = (i & 1) * 64;
      *(uint4*)&sA[buf][chunk][half + lane] = pack8(fa[i][0], fa[i][1]);
    }
#pragma unroll
    for (int i = 0; i < 2; ++i) {
      const int chunk = 2 * w + i;
      *(uint4*)&sB[buf][chunk][lane] = pack8(fb[i][0], fb[i][1]);
    }
  };

  stage_load(0);
  stage_write(0);
  __syncthreads();
  for (int kt = 0; kt < 8; ++kt) {
    const int buf = kt & 1;
    if (kt + 1 < 8) stage_load(kt + 1);      // issue loads; latency hides under MFMAs
#pragma unroll
    for (int c = 0; c < 2; ++c) {
      bf16x8 af0 = sA[buf][c * 4 + quad][w * 32 + l];
      bf16x8 af1 = sA[buf][c * 4 + quad][w * 32 + 16 + l];
#pragma unroll
      for (int s = 0; s < 4; ++s) {
        bf16x8 bfb = sB[buf][c * 4 + quad][s * 16 + l];
        acc[0][s] = __builtin_amdgcn_mfma_f32_16x16x32_bf16(af0, bfb, acc[0][s], 0, 0, 0);
        acc[1][s] = __builtin_amdgcn_mfma_f32_16x16x32_bf16(af1, bfb, acc[1][s], 0, 0, 0);
      }
    }
    if (kt + 1 < 8) stage_write(buf ^ 1);    // cvt + LDS write after compute
    __syncthreads();
  }

#pragma unroll
  for (int m = 0; m < 2; ++m)
#pragma unroll
    for (int s = 0; s < 4; ++s) {
      int j = j0 + s * 16 + l;
      float bv = bias[j];
      int n0 = m0 + w * 32 + m * 16 + quad * 4;
      if (z < 2) {
        u16* Y = (z == 0) ? Qs : Ks;
#pragma unroll
        for (int r = 0; r < 4; ++r)
          Y[(size_t)(n0 + r) * DMODEL + j] = f2bf(acc[m][s][r] + bv);
      } else {
        ushort4 pk;
        pk.x = f2bf(acc[m][s][0] + bv); pk.y = f2bf(acc[m][s][1] + bv);
        pk.z = f2bf(acc[m][s][2] + bv); pk.w = f2bf(acc[m][s][3] + bv);
        *(ushort4*)(Vt + (size_t)j * N_TOK + n0) = pk;   // V^T write
      }
    }
}

// ---------------------------------------------------------------------------
// Kernel 2: flash attention — r16 verified config (42.6-44.7us, absmax
// 0.03125, conflicts 2.1M): r8 geometry + r14 VALU diet + pbuf XOR-swizzle
// (byte ^= ((l&7)<<4) on both uint2 writes and uint4 reads, 128B rows).
// FROZEN — remaining conflicts are staging-vs-compute contention; attn is
// within ~2us of its pbuf-free floor.
// ---------------------------------------------------------------------------
__global__ __launch_bounds__(512, 4) void attn_kernel(
    const u16* __restrict__ Qs, const u16* __restrict__ Ks,
    const u16* __restrict__ Vt, u16* __restrict__ Opart, float* __restrict__ Lpart)
{
  const int hs = blockIdx.x;                 // h + 8*split
  const int h = hs & 7, split = hs >> 3;
  const int qt = blockIdx.y;
  const int tid = threadIdx.x;
  const int w = tid >> 6, lane = tid & 63, quad = lane >> 4, l = lane & 15;

  __shared__ bf16x8 kch[2][8][64];                 // 16 KB  [buf][d-chunk][key]
  __shared__ bf16x8 vch[2][8][64];                 // 16 KB  [buf][key-chunk][vd]
  __shared__ __align__(128) u16 pbuf[8][32][64];   // 32 KB  [wave][q][128B swizzled row]

  const int wq0 = qt * 256 + w * 32;

  // Q fragments (B-operand), pre-scaled by log2(e)/8
  bf16x8 qf[2][2];
#pragma unroll
  for (int c = 0; c < 2; ++c)
#pragma unroll
    for (int m = 0; m < 2; ++m) {
      U128 u;
      u.u = *(const uint4*)(Qs + (size_t)(wq0 + m * 16 + l) * DMODEL + h * HDIM + c * 32 + quad * 8);
#pragma unroll
      for (int j = 0; j < 8; ++j) u.s[j] = f2bf(bf2f(u.s[j]) * 0.18033688f);
      qf[c][m] = u.b;
    }

  // all-ones B-fragment for the lsum MFMA (bf16 1.0 = 0x3F80)
  U128 onesu;
#pragma unroll
  for (int j = 0; j < 8; ++j) onesu.s[j] = 0x3F80;

  const f32x4 zero = {0.f, 0.f, 0.f, 0.f};
  f32x4 o[2][4];
  f32x4 ol[2];               // lsum accumulators: ol[m][r] = lsum[q=m*16+quad*4+r]
  ol[0] = zero; ol[1] = zero;
#pragma unroll
  for (int m = 0; m < 2; ++m)
#pragma unroll
    for (int s = 0; s < 4; ++s) o[m][s] = zero;

  auto stage = [&](int it, int buf) {
    const int j0 = split * 1024 + it * 64;
    if (w < 4) {            // waves 0-3 stage K (8 KB)
      const u16* kg = Ks + (size_t)(j0 + lane) * DMODEL + h * HDIM + w * 16;
      ldg2lds16(kg,     (char*)&kch[buf][2 * w][0]);
      ldg2lds16(kg + 8, (char*)&kch[buf][2 * w + 1][0]);
    } else {                // waves 4-7 stage V^T (8 KB)
      const int w2 = w - 4;
      const u16* vg = Vt + (size_t)(h * HDIM + lane) * N_TOK + j0 + w2 * 16;
      ldg2lds16(vg,     (char*)&vch[buf][2 * w2][0]);
      ldg2lds16(vg + 8, (char*)&vch[buf][2 * w2 + 1][0]);
    }
  };

  stage(0, 0);
  __syncthreads();

  const unsigned swz = (unsigned)((l & 7) << 4);   // per-row XOR (row&7 == l&7)

  for (int it = 0; it < 16; ++it) {
    const int buf = it & 1;
    if (it + 1 < 16) stage(it + 1, buf ^ 1);   // prefetch overlaps compute

#pragma unroll
    for (int kh = 0; kh < 2; ++kh) {           // two 32-key halves
#pragma unroll
      for (int tt = 0; tt < 2; ++tt) {
        const int t = kh * 2 + tt;
        f32x4 sacc[2];
        sacc[0] = zero; sacc[1] = zero;
#pragma unroll
        for (int c = 0; c < 2; ++c) {
          bf16x8 kf = kch[buf][c * 4 + quad][t * 16 + l];
          sacc[0] = __builtin_amdgcn_mfma_f32_16x16x32_bf16(kf, qf[c][0], sacc[0], 0, 0, 0);
          sacc[1] = __builtin_amdgcn_mfma_f32_16x16x32_bf16(kf, qf[c][1], sacc[1], 0, 0, 0);
        }
#pragma unroll
        for (int m = 0; m < 2; ++m) {
          uint2 st;
          st.x = cvtpk(EXP2(sacc[m][0]), EXP2(sacc[m][1]));
          st.y = cvtpk(EXP2(sacc[m][2]), EXP2(sacc[m][3]));
          char* pb = (char*)&pbuf[w][m * 16 + l][0];
          *(uint2*)(pb + (((unsigned)(tt * 32 + quad * 8)) ^ swz)) = st;
        }
      }
      // PV for this key half (contraction = 32 keys, quad covers them)
      U128 pf0, pf1;
      const unsigned ro = ((unsigned)(quad * 16)) ^ swz;
      pf0.u = *(const uint4*)((const char*)&pbuf[w][l][0] + ro);
      pf1.u = *(const uint4*)((const char*)&pbuf[w][16 + l][0] + ro);
#pragma unroll
      for (int s = 0; s < 4; ++s) {
        bf16x8 vf = vch[buf][kh * 4 + quad][s * 16 + l];
        o[0][s] = __builtin_amdgcn_mfma_f32_16x16x32_bf16(pf0.b, vf, o[0][s], 0, 0, 0);
        o[1][s] = __builtin_amdgcn_mfma_f32_16x16x32_bf16(pf1.b, vf, o[1][s], 0, 0, 0);
      }
      // lsum = P . 1 on the matrix pipe
      ol[0] = __builtin_amdgcn_mfma_f32_16x16x32_bf16(pf0.b, onesu.b, ol[0], 0, 0, 0);
      ol[1] = __builtin_amdgcn_mfma_f32_16x16x32_bf16(pf1.b, onesu.b, ol[1], 0, 0, 0);
    }
    __syncthreads();   // publishes next buf's loads; orders buf reuse
  }

  // ol[m][r] holds lsum for q = m*16+quad*4+r, replicated across l=0..15.
  if (l == 0) {
    float* Lp = Lpart + ((size_t)split * NHEADS + h) * N_TOK + wq0;
#pragma unroll
    for (int m = 0; m < 2; ++m)
#pragma unroll
      for (int r = 0; r < 4; ++r)
        Lp[m * 16 + quad * 4 + r] = ol[m][r];
  }
  // Opart[split][h][q][vd] bf16 (unnormalized)
  u16* Ob = Opart + ((size_t)(split * NHEADS + h) * N_TOK + wq0) * 64;
#pragma unroll
  for (int m = 0; m < 2; ++m)
#pragma unroll
    for (int s = 0; s < 4; ++s)
#pragma unroll
      for (int r = 0; r < 4; ++r)
        Ob[(size_t)(m * 16 + quad * 4 + r) * 64 + s * 16 + l] = f2bf(o[m][s][r]);
}

// ---------------------------------------------------------------------------
// Kernel 3 (r19): fused combine + output-GEMM + LayerNorm, now reading WO
// fp32 directly (reg-staged cvt, async-STAGE split) — WOb buffer deleted.
// Layouts/reads/MFMA order identical to r18's outfuse (bit-identical GEMM).
// grid 256 x 1024 thr (16 waves), block owns 16 token rows.
// ---------------------------------------------------------------------------
__global__ __launch_bounds__(1024) void outfuse_kernel(
    const u16* __restrict__ Opart, const float* __restrict__ Lpart,
    const float* __restrict__ WO, const float* __restrict__ bO,
    const float* __restrict__ resid, const float* __restrict__ gamma,
    const float* __restrict__ beta, float* __restrict__ Y)
{
  __shared__ __align__(128) char smem[16384 + 2 * 65536];   // 144 KB
  bf16x8* sA = (bf16x8*)smem;                 // [64 col8][16 n]   (16 KB)
  bf16x8* sB = (bf16x8*)(smem + 16384);       // [2][512 j][8 ch'] (2x64 KB)
  float* pls = (float*)smem;                  // reused after GEMM: [16 row][16 wave]
  float* plq = (float*)smem + 256;
  float* mrow = (float*)smem + 512;           // [16][2] mu, inv-sigma

  const int tid = threadIdx.x;
  const int w = tid >> 6, lane = tid & 63, quad = lane >> 4, l = lane & 15;
  const int n0 = blockIdx.x * 16;

  // ---- B staging (reg-staged fp32->bf16): wave w covers j = w*32..+31;
  //      lane supplies j = jb + (lane>>3), LDS slot ch' = lane&7 holding
  //      global k-chunk (lane&7)^(lane>>3)  (read-side swz: ch' = kc^(j&7)).
  float4 fw[4][2];
  auto stageB_load = [&](int kt) {
#pragma unroll
    for (int t = 0; t < 4; ++t) {
      const int jb = w * 32 + t * 8;
      const float* g = WO + (size_t)(jb + (lane >> 3)) * DMODEL + kt * 64
                     + (((lane & 7) ^ (lane >> 3)) * 8);
      fw[t][0] = *(const float4*)g;
      fw[t][1] = *(const float4*)(g + 4);
    }
  };
  auto stageB_write = [&](int buf) {
#pragma unroll
    for (int t = 0; t < 4; ++t) {
      const int jb = w * 32 + t * 8;
      *(uint4*)&sB[(size_t)buf * 4096 + jb * 8 + lane] = pack8(fw[t][0], fw[t][1]);
    }
  };

  stageB_load(0);

  // ---- phase 1: combine -> sA (ctx tile [16 rows][512 cols] as [col8][n])
  {
    const int h = tid >> 7;
    const int n = (tid >> 3) & 15;
    const int vd0 = (tid & 7) * 8;
    float a8[8] = {0, 0, 0, 0, 0, 0, 0, 0};
    float lsum = 0.f;
#pragma unroll
    for (int s = 0; s < 4; ++s) {
      U128 u;
      u.u = *(const uint4*)(Opart + ((size_t)(s * NHEADS + h) * N_TOK + n0 + n) * 64 + vd0);
#pragma unroll
      for (int j = 0; j < 8; ++j) a8[j] += bf2f(u.s[j]);
      lsum += Lpart[((size_t)s * NHEADS + h) * N_TOK + n0 + n];
    }
    float inv = 1.f / lsum;
    U128 o;
#pragma unroll
    for (int j = 0; j < 8; ++j) o.s[j] = f2bf(a8[j] * inv);
    const int col8 = h * 8 + (tid & 7);
    *(uint4*)&sA[col8 * 16 + n] = o.u;
  }
  stageB_write(0);
  __syncthreads();

  // ---- phase 2: GEMM out[16][512] = ctx . WO^T, wave w -> j in [w*32, w*32+32)
  const f32x4 zero = {0.f, 0.f, 0.f, 0.f};
  f32x4 acc[2];
  acc[0] = zero; acc[1] = zero;

  for (int kt = 0; kt < 8; ++kt) {
    const int buf = kt & 1;
    if (kt + 1 < 8) stageB_load(kt + 1);     // issue loads; hide under MFMAs
#pragma unroll
    for (int c = 0; c < 2; ++c) {
      bf16x8 af = sA[(kt * 8 + c * 4 + quad) * 16 + l];
#pragma unroll
      for (int s = 0; s < 2; ++s) {
        const int j = w * 32 + s * 16 + l;
        bf16x8 bfb = sB[(size_t)buf * 4096 + j * 8 + ((c * 4 + quad) ^ (l & 7))];
        acc[s] = __builtin_amdgcn_mfma_f32_16x16x32_bf16(af, bfb, acc[s], 0, 0, 0);
      }
    }
    if (kt + 1 < 8) stageB_write(buf ^ 1);   // cvt + LDS write after compute
    __syncthreads();
  }

  // ---- phase 3: bias + residual, LN, write
  float vb[2][4];
#pragma unroll
  for (int s = 0; s < 2; ++s) {
    const int j = w * 32 + s * 16 + l;
    const float bv = bO[j];
#pragma unroll
    for (int r = 0; r < 4; ++r)
      vb[s][r] = acc[s][r] + bv + resid[(size_t)(n0 + quad * 4 + r) * DMODEL + j];
  }
#pragma unroll
  for (int r = 0; r < 4; ++r) {
    float sm = vb[0][r] + vb[1][r];
    float sq = vb[0][r] * vb[0][r] + vb[1][r] * vb[1][r];
#pragma unroll
    for (int mk = 1; mk < 16; mk <<= 1) {
      sm += __shfl_xor(sm, mk);
      sq += __shfl_xor(sq, mk);
    }
    if (l == 0) {
      pls[(quad * 4 + r) * 16 + w] = sm;
      plq[(quad * 4 + r) * 16 + w] = sq;
    }
  }
  __syncthreads();
  if (tid < 16) {
    float sm = 0.f, sq = 0.f;
#pragma unroll
    for (int w2 = 0; w2 < 16; ++w2) { sm += pls[tid * 16 + w2]; sq += plq[tid * 16 + w2]; }
    const float mu = sm * (1.f / DMODEL);
    const float var = sq * (1.f / DMODEL) - mu * mu;
    mrow[tid * 2]     = mu;
    mrow[tid * 2 + 1] = rsqrtf(var + 1e-5f);
  }
  __syncthreads();
#pragma unroll
  for (int s = 0; s < 2; ++s) {
    const int j = w * 32 + s * 16 + l;
    const float gj = gamma[j], bj = beta[j];
#pragma unroll
    for (int r = 0; r < 4; ++r) {
      const int row = quad * 4 + r;
      const float mu = mrow[row * 2], sc = mrow[row * 2 + 1];
      Y[(size_t)(n0 + row) * DMODEL + j] = (vb[s][r] - mu) * sc * gj + bj;
    }
  }
}

// ---------------------------------------------------------------------------
extern "C" void kernel_launch(void* const* d_in, const int* in_sizes, int n_in,
                              void* d_out, int out_size, void* d_ws, size_t ws_size,
                              hipStream_t stream)
{
  const float* Q     = (const float*)d_in[0];
  const float* K     = (const float*)d_in[1];
  const float* V     = (const float*)d_in[2];
  const float* WQ    = (const float*)d_in[3];
  const float* bQ    = (const float*)d_in[4];
  const float* WK    = (const float*)d_in[5];
  const float* bK    = (const float*)d_in[6];
  const float* WV    = (const float*)d_in[7];
  const float* bV    = (const float*)d_in[8];
  const float* WO    = (const float*)d_in[9];
  const float* bO    = (const float*)d_in[10];
  const float* gamma = (const float*)d_in[11];
  const float* beta  = (const float*)d_in[12];

  const size_t MB = 1ull << 20;
  char* ws = (char*)d_ws;
  u16* Qs   = (u16*)(ws + 0 * MB);                  // 4 MB each
  u16* Ks   = (u16*)(ws + 4 * MB);
  u16* Vt   = (u16*)(ws + 8 * MB);                  // projected V^T [j][n]
  u16* Opart = (u16*)(ws + 12 * MB);                // 16 MB bf16
  float* Lpart = (float*)(ws + 28 * MB);            // 0.5 MB
  float* out = (float*)d_out;

  proj3_kernel<<<dim3(32, 8, 3), 256, 0, stream>>>(Q, K, V, WQ, WK, WV,
                                                   bQ, bK, bV, Qs, Ks, Vt);
  attn_kernel<<<dim3(32, 16), 512, 0, stream>>>(Qs, Ks, Vt, Opart, Lpart);
  outfuse_kernel<<<256, 1024, 0, stream>>>(Opart, Lpart, WO, bO, Q,
                                           gamma, beta, out);
}

// Round 10
// 165.344 us; speedup vs baseline: 1.1300x; 1.1300x over previous
//
#include <hip/hip_runtime.h>
#include <cstdint>

#define N_TOK 4096
#define DMODEL 512
#define NHEADS 8
#define HDIM 64

typedef unsigned short u16;
typedef __bf16 bf16x8 __attribute__((ext_vector_type(8)));
typedef float f32x4 __attribute__((ext_vector_type(4)));

union U128 { uint4 u; bf16x8 b; u16 s[8]; };

__device__ __forceinline__ u16 f2bf(float f) {           // RNE
  uint32_t u = __builtin_bit_cast(uint32_t, f);
  u += 0x7FFFu + ((u >> 16) & 1u);
  return (u16)(u >> 16);
}
__device__ __forceinline__ float bf2f(u16 s) {
  uint32_t u = ((uint32_t)s) << 16;
  return __builtin_bit_cast(float, u);
}

#if __has_builtin(__builtin_amdgcn_exp2f)
#define EXP2(x) __builtin_amdgcn_exp2f(x)
#else
#define EXP2(x) __expf((x) * 0.6931471805599453f)
#endif

// v_cvt_pk_bf16_f32: packs two f32 into one u32 of 2 bf16 (RNE), src0 -> lo.
__device__ __forceinline__ uint32_t cvtpk(float lo, float hi) {
  uint32_t r;
  asm("v_cvt_pk_bf16_f32 %0, %1, %2" : "=v"(r) : "v"(lo), "v"(hi));
  return r;
}

// async global->LDS, 16B/lane, dest = wave-uniform base + lane*16
__device__ __forceinline__ void ldg2lds16(const void* g, void* s) {
  __builtin_amdgcn_global_load_lds(
      (const __attribute__((address_space(1))) void*)g,
      (__attribute__((address_space(3))) void*)s, 16, 0, 0);
}

// ---------------------------------------------------------------------------
// Kernel 0: fp32 -> bf16 pre-convert of Q,K,V,WQ,WK,WV,WO.  7168 x 256.
// RESTORED (r19 lesson: deleting this traded a coalesced linear pass for 2x
// instructions on proj3's scattered staging path — net loss.  Conversion
// belongs in coalesced streaming passes; staging stays bf16.)
// ---------------------------------------------------------------------------
__global__ __launch_bounds__(256) void cvt7_kernel(
    const float* __restrict__ Q, const float* __restrict__ K, const float* __restrict__ V,
    const float* __restrict__ WQ, const float* __restrict__ WK, const float* __restrict__ WV,
    const float* __restrict__ WO,
    u16* __restrict__ Qb, u16* __restrict__ Kb, u16* __restrict__ Vb,
    u16* __restrict__ WQb, u16* __restrict__ WKb, u16* __restrict__ WVb,
    u16* __restrict__ WOb)
{
  int b = blockIdx.x;
  const float* src; u16* dst; int rel;
  if      (b < 2048) { src = Q;  dst = Qb;  rel = b; }
  else if (b < 4096) { src = K;  dst = Kb;  rel = b - 2048; }
  else if (b < 6144) { src = V;  dst = Vb;  rel = b - 4096; }
  else if (b < 6400) { src = WQ; dst = WQb; rel = b - 6144; }
  else if (b < 6656) { src = WK; dst = WKb; rel = b - 6400; }
  else if (b < 6912) { src = WV; dst = WVb; rel = b - 6656; }
  else               { src = WO; dst = WOb; rel = b - 6912; }
  int i = (rel * 256 + threadIdx.x) * 4;
  float4 f = *(const float4*)(src + i);
  ushort4 o;
  o.x = f2bf(f.x); o.y = f2bf(f.y); o.z = f2bf(f.z); o.w = f2bf(f.w);
  *(ushort4*)(dst + i) = o;
}

// ---------------------------------------------------------------------------
// Kernel 1 (r20): fused QKV projection, bf16 in (r18 base) with COALESCED
// staging.  r19 diagnosed proj3 as transaction-bound: old staging was
// row-scattered (lane->row, 64x16B discrete txns/inst).  New: each
// global_load_lds covers 8 CONSECUTIVE rows x 128B (8 lanes/row) = 8
// coalesced txns/inst (8x less TA pressure).  Row-major LDS [row][slot]
// with rule-21c swizzle (proven in outfuse): linear LDS dest + source
// chunk pre-XOR slot^(row&7) + read slot (c*4+quad)^(l&7).  Fragment rows
// w*32+l / w*32+16+l / s*16+l all have &7 == l&7 -> keys agree; fragments
// get the SAME global elements as r18 -> bit-identical (absmax 0.03125).
// 128x64 tile, m=2, double-buffered.  grid (32, 8, 3), block 256.
// ---------------------------------------------------------------------------
__global__ __launch_bounds__(256) void proj3_kernel(
    const u16* __restrict__ Qb, const u16* __restrict__ Kb, const u16* __restrict__ Vb,
    const u16* __restrict__ WQb, const u16* __restrict__ WKb, const u16* __restrict__ WVb,
    const float* __restrict__ bQ, const float* __restrict__ bK, const float* __restrict__ bV,
    u16* __restrict__ Qs, u16* __restrict__ Ks, u16* __restrict__ Vt)
{
  const int z = blockIdx.z;
  const u16* A      = (z == 0) ? Qb : (z == 1) ? Kb : Vb;
  const u16* W      = (z == 0) ? WQb : (z == 1) ? WKb : WVb;
  const float* bias = (z == 0) ? bQ : (z == 1) ? bK : bV;

  const int m0 = blockIdx.x * 128;
  const int j0 = blockIdx.y * 64;
  const int tid = threadIdx.x;
  const int w = tid >> 6, lane = tid & 63, quad = lane >> 4, l = lane & 15;

  __shared__ bf16x8 sA[2][128 * 8];  // [row][slot] 32 KB
  __shared__ bf16x8 sB[2][64 * 8];   // [row][slot] 16 KB

  const f32x4 zero = {0.f, 0.f, 0.f, 0.f};
  f32x4 acc[2][4];
#pragma unroll
  for (int m = 0; m < 2; ++m)
#pragma unroll
    for (int s = 0; s < 4; ++s) acc[m][s] = zero;

  const int rsub = lane >> 3;          // 0..7: row within 8-row group
  const int gchunk = (lane & 7) ^ rsub;  // pre-swizzled source k-chunk

  auto stage = [&](int kt, int buf) {
    const int k0 = kt * 64;
#pragma unroll
    for (int t = 0; t < 4; ++t) {
      const int row = w * 32 + t * 8;
      const u16* ag = A + (size_t)(m0 + row + rsub) * DMODEL + k0 + gchunk * 8;
      ldg2lds16(ag, (char*)&sA[buf][row * 8]);
    }
#pragma unroll
    for (int i = 0; i < 2; ++i) {
      const int row = w * 16 + i * 8;
      const u16* bg = W + (size_t)(j0 + row + rsub) * DMODEL + k0 + gchunk * 8;
      ldg2lds16(bg, (char*)&sB[buf][row * 8]);
    }
  };

  stage(0, 0);
  __syncthreads();
  for (int kt = 0; kt < 8; ++kt) {
    const int buf = kt & 1;
    if (kt + 1 < 8) stage(kt + 1, buf ^ 1);
#pragma unroll
    for (int c = 0; c < 2; ++c) {
      const int sl = (c * 4 + quad) ^ (l & 7);   // swizzled read slot
      bf16x8 af0 = sA[buf][(w * 32 + l) * 8 + sl];
      bf16x8 af1 = sA[buf][(w * 32 + 16 + l) * 8 + sl];
#pragma unroll
      for (int s = 0; s < 4; ++s) {
        bf16x8 bfb = sB[buf][(s * 16 + l) * 8 + sl];
        acc[0][s] = __builtin_amdgcn_mfma_f32_16x16x32_bf16(af0, bfb, acc[0][s], 0, 0, 0);
        acc[1][s] = __builtin_amdgcn_mfma_f32_16x16x32_bf16(af1, bfb, acc[1][s], 0, 0, 0);
      }
    }
    __syncthreads();
  }

#pragma unroll
  for (int m = 0; m < 2; ++m)
#pragma unroll
    for (int s = 0; s < 4; ++s) {
      int j = j0 + s * 16 + l;
      float bv = bias[j];
      int n0 = m0 + w * 32 + m * 16 + quad * 4;
      if (z < 2) {
        u16* Y = (z == 0) ? Qs : Ks;
#pragma unroll
        for (int r = 0; r < 4; ++r)
          Y[(size_t)(n0 + r) * DMODEL + j] = f2bf(acc[m][s][r] + bv);
      } else {
        ushort4 pk;
        pk.x = f2bf(acc[m][s][0] + bv); pk.y = f2bf(acc[m][s][1] + bv);
        pk.z = f2bf(acc[m][s][2] + bv); pk.w = f2bf(acc[m][s][3] + bv);
        *(ushort4*)(Vt + (size_t)j * N_TOK + n0) = pk;   // V^T write
      }
    }
}

// ---------------------------------------------------------------------------
// Kernel 2: flash attention — r16 verified config (44.5us, absmax 0.03125,
// conflicts 2.1M): r8 geometry + r14 VALU diet + pbuf XOR-swizzle.  FROZEN.
// ---------------------------------------------------------------------------
__global__ __launch_bounds__(512, 4) void attn_kernel(
    const u16* __restrict__ Qs, const u16* __restrict__ Ks,
    const u16* __restrict__ Vt, u16* __restrict__ Opart, float* __restrict__ Lpart)
{
  const int hs = blockIdx.x;                 // h + 8*split
  const int h = hs & 7, split = hs >> 3;
  const int qt = blockIdx.y;
  const int tid = threadIdx.x;
  const int w = tid >> 6, lane = tid & 63, quad = lane >> 4, l = lane & 15;

  __shared__ bf16x8 kch[2][8][64];                 // 16 KB  [buf][d-chunk][key]
  __shared__ bf16x8 vch[2][8][64];                 // 16 KB  [buf][key-chunk][vd]
  __shared__ __align__(128) u16 pbuf[8][32][64];   // 32 KB  [wave][q][128B swizzled row]

  const int wq0 = qt * 256 + w * 32;

  // Q fragments (B-operand), pre-scaled by log2(e)/8
  bf16x8 qf[2][2];
#pragma unroll
  for (int c = 0; c < 2; ++c)
#pragma unroll
    for (int m = 0; m < 2; ++m) {
      U128 u;
      u.u = *(const uint4*)(Qs + (size_t)(wq0 + m * 16 + l) * DMODEL + h * HDIM + c * 32 + quad * 8);
#pragma unroll
      for (int j = 0; j < 8; ++j) u.s[j] = f2bf(bf2f(u.s[j]) * 0.18033688f);
      qf[c][m] = u.b;
    }

  // all-ones B-fragment for the lsum MFMA (bf16 1.0 = 0x3F80)
  U128 onesu;
#pragma unroll
  for (int j = 0; j < 8; ++j) onesu.s[j] = 0x3F80;

  const f32x4 zero = {0.f, 0.f, 0.f, 0.f};
  f32x4 o[2][4];
  f32x4 ol[2];               // lsum accumulators: ol[m][r] = lsum[q=m*16+quad*4+r]
  ol[0] = zero; ol[1] = zero;
#pragma unroll
  for (int m = 0; m < 2; ++m)
#pragma unroll
    for (int s = 0; s < 4; ++s) o[m][s] = zero;

  auto stage = [&](int it, int buf) {
    const int j0 = split * 1024 + it * 64;
    if (w < 4) {            // waves 0-3 stage K (8 KB)
      const u16* kg = Ks + (size_t)(j0 + lane) * DMODEL + h * HDIM + w * 16;
      ldg2lds16(kg,     (char*)&kch[buf][2 * w][0]);
      ldg2lds16(kg + 8, (char*)&kch[buf][2 * w + 1][0]);
    } else {                // waves 4-7 stage V^T (8 KB)
      const int w2 = w - 4;
      const u16* vg = Vt + (size_t)(h * HDIM + lane) * N_TOK + j0 + w2 * 16;
      ldg2lds16(vg,     (char*)&vch[buf][2 * w2][0]);
      ldg2lds16(vg + 8, (char*)&vch[buf][2 * w2 + 1][0]);
    }
  };

  stage(0, 0);
  __syncthreads();

  const unsigned swz = (unsigned)((l & 7) << 4);   // per-row XOR (row&7 == l&7)

  for (int it = 0; it < 16; ++it) {
    const int buf = it & 1;
    if (it + 1 < 16) stage(it + 1, buf ^ 1);   // prefetch overlaps compute

#pragma unroll
    for (int kh = 0; kh < 2; ++kh) {           // two 32-key halves
#pragma unroll
      for (int tt = 0; tt < 2; ++tt) {
        const int t = kh * 2 + tt;
        f32x4 sacc[2];
        sacc[0] = zero; sacc[1] = zero;
#pragma unroll
        for (int c = 0; c < 2; ++c) {
          bf16x8 kf = kch[buf][c * 4 + quad][t * 16 + l];
          sacc[0] = __builtin_amdgcn_mfma_f32_16x16x32_bf16(kf, qf[c][0], sacc[0], 0, 0, 0);
          sacc[1] = __builtin_amdgcn_mfma_f32_16x16x32_bf16(kf, qf[c][1], sacc[1], 0, 0, 0);
        }
#pragma unroll
        for (int m = 0; m < 2; ++m) {
          uint2 st;
          st.x = cvtpk(EXP2(sacc[m][0]), EXP2(sacc[m][1]));
          st.y = cvtpk(EXP2(sacc[m][2]), EXP2(sacc[m][3]));
          char* pb = (char*)&pbuf[w][m * 16 + l][0];
          *(uint2*)(pb + (((unsigned)(tt * 32 + quad * 8)) ^ swz)) = st;
        }
      }
      // PV for this key half (contraction = 32 keys, quad covers them)
      U128 pf0, pf1;
      const unsigned ro = ((unsigned)(quad * 16)) ^ swz;
      pf0.u = *(const uint4*)((const char*)&pbuf[w][l][0] + ro);
      pf1.u = *(const uint4*)((const char*)&pbuf[w][16 + l][0] + ro);
#pragma unroll
      for (int s = 0; s < 4; ++s) {
        bf16x8 vf = vch[buf][kh * 4 + quad][s * 16 + l];
        o[0][s] = __builtin_amdgcn_mfma_f32_16x16x32_bf16(pf0.b, vf, o[0][s], 0, 0, 0);
        o[1][s] = __builtin_amdgcn_mfma_f32_16x16x32_bf16(pf1.b, vf, o[1][s], 0, 0, 0);
      }
      // lsum = P . 1 on the matrix pipe
      ol[0] = __builtin_amdgcn_mfma_f32_16x16x32_bf16(pf0.b, onesu.b, ol[0], 0, 0, 0);
      ol[1] = __builtin_amdgcn_mfma_f32_16x16x32_bf16(pf1.b, onesu.b, ol[1], 0, 0, 0);
    }
    __syncthreads();   // publishes next buf's loads; orders buf reuse
  }

  // ol[m][r] holds lsum for q = m*16+quad*4+r, replicated across l=0..15.
  if (l == 0) {
    float* Lp = Lpart + ((size_t)split * NHEADS + h) * N_TOK + wq0;
#pragma unroll
    for (int m = 0; m < 2; ++m)
#pragma unroll
      for (int r = 0; r < 4; ++r)
        Lp[m * 16 + quad * 4 + r] = ol[m][r];
  }
  // Opart[split][h][q][vd] bf16 (unnormalized)
  u16* Ob = Opart + ((size_t)(split * NHEADS + h) * N_TOK + wq0) * 64;
#pragma unroll
  for (int m = 0; m < 2; ++m)
#pragma unroll
    for (int s = 0; s < 4; ++s)
#pragma unroll
      for (int r = 0; r < 4; ++r)
        Ob[(size_t)(m * 16 + quad * 4 + r) * 64 + s * 16 + l] = f2bf(o[m][s][r]);
}

// ---------------------------------------------------------------------------
// Kernel 3: fused combine + output-GEMM + LayerNorm (r18 verified version,
// WOb bf16 via global_load_lds with rule-21c swizzle).
// grid 256 x 1024 thr (16 waves), block owns 16 token rows.
// ---------------------------------------------------------------------------
__global__ __launch_bounds__(1024) void outfuse_kernel(
    const u16* __restrict__ Opart, const float* __restrict__ Lpart,
    const u16* __restrict__ WOb, const float* __restrict__ bO,
    const float* __restrict__ resid, const float* __restrict__ gamma,
    const float* __restrict__ beta, float* __restrict__ Y)
{
  __shared__ __align__(128) char smem[16384 + 2 * 65536];   // 144 KB
  bf16x8* sA = (bf16x8*)smem;                 // [64 col8][16 n]   (16 KB)
  bf16x8* sB = (bf16x8*)(smem + 16384);       // [2][512 j][8 ch'] (2x64 KB)
  float* pls = (float*)smem;                  // reused after GEMM: [16 row][16 wave]
  float* plq = (float*)smem + 256;
  float* mrow = (float*)smem + 512;           // [16][2] mu, inv-sigma

  const int tid = threadIdx.x;
  const int w = tid >> 6, lane = tid & 63, quad = lane >> 4, l = lane & 15;
  const int n0 = blockIdx.x * 16;

  auto stageB = [&](int kt, int buf) {
#pragma unroll
    for (int t = 0; t < 4; ++t) {
      const int jb = w * 32 + t * 8;
      const u16* g = WOb + (size_t)(jb + (lane >> 3)) * DMODEL + kt * 64
                   + (((lane & 7) ^ (lane >> 3)) * 8);
      ldg2lds16(g, (char*)&sB[(size_t)buf * 4096 + jb * 8]);
    }
  };

  stageB(0, 0);

  // ---- phase 1: combine -> sA (ctx tile [16 rows][512 cols] as [col8][n])
  {
    const int h = tid >> 7;
    const int n = (tid >> 3) & 15;
    const int vd0 = (tid & 7) * 8;
    float a8[8] = {0, 0, 0, 0, 0, 0, 0, 0};
    float lsum = 0.f;
#pragma unroll
    for (int s = 0; s < 4; ++s) {
      U128 u;
      u.u = *(const uint4*)(Opart + ((size_t)(s * NHEADS + h) * N_TOK + n0 + n) * 64 + vd0);
#pragma unroll
      for (int j = 0; j < 8; ++j) a8[j] += bf2f(u.s[j]);
      lsum += Lpart[((size_t)s * NHEADS + h) * N_TOK + n0 + n];
    }
    float inv = 1.f / lsum;
    U128 o;
#pragma unroll
    for (int j = 0; j < 8; ++j) o.s[j] = f2bf(a8[j] * inv);
    const int col8 = h * 8 + (tid & 7);
    *(uint4*)&sA[col8 * 16 + n] = o.u;
  }
  __syncthreads();

  // ---- phase 2: GEMM out[16][512] = ctx . WOb^T, wave w -> j in [w*32, w*32+32)
  const f32x4 zero = {0.f, 0.f, 0.f, 0.f};
  f32x4 acc[2];
  acc[0] = zero; acc[1] = zero;

  for (int kt = 0; kt < 8; ++kt) {
    const int buf = kt & 1;
    if (kt + 1 < 8) stageB(kt + 1, buf ^ 1);
#pragma unroll
    for (int c = 0; c < 2; ++c) {
      bf16x8 af = sA[(kt * 8 + c * 4 + quad) * 16 + l];
#pragma unroll
      for (int s = 0; s < 2; ++s) {
        const int j = w * 32 + s * 16 + l;
        bf16x8 bfb = sB[(size_t)buf * 4096 + j * 8 + ((c * 4 + quad) ^ (l & 7))];
        acc[s] = __builtin_amdgcn_mfma_f32_16x16x32_bf16(af, bfb, acc[s], 0, 0, 0);
      }
    }
    __syncthreads();
  }

  // ---- phase 3: bias + residual, LN, write
  float vb[2][4];
#pragma unroll
  for (int s = 0; s < 2; ++s) {
    const int j = w * 32 + s * 16 + l;
    const float bv = bO[j];
#pragma unroll
    for (int r = 0; r < 4; ++r)
      vb[s][r] = acc[s][r] + bv + resid[(size_t)(n0 + quad * 4 + r) * DMODEL + j];
  }
#pragma unroll
  for (int r = 0; r < 4; ++r) {
    float sm = vb[0][r] + vb[1][r];
    float sq = vb[0][r] * vb[0][r] + vb[1][r] * vb[1][r];
#pragma unroll
    for (int mk = 1; mk < 16; mk <<= 1) {
      sm += __shfl_xor(sm, mk);
      sq += __shfl_xor(sq, mk);
    }
    if (l == 0) {
      pls[(quad * 4 + r) * 16 + w] = sm;
      plq[(quad * 4 + r) * 16 + w] = sq;
    }
  }
  __syncthreads();
  if (tid < 16) {
    float sm = 0.f, sq = 0.f;
#pragma unroll
    for (int w2 = 0; w2 < 16; ++w2) { sm += pls[tid * 16 + w2]; sq += plq[tid * 16 + w2]; }
    const float mu = sm * (1.f / DMODEL);
    const float var = sq * (1.f / DMODEL) - mu * mu;
    mrow[tid * 2]     = mu;
    mrow[tid * 2 + 1] = rsqrtf(var + 1e-5f);
  }
  __syncthreads();
#pragma unroll
  for (int s = 0; s < 2; ++s) {
    const int j = w * 32 + s * 16 + l;
    const float gj = gamma[j], bj = beta[j];
#pragma unroll
    for (int r = 0; r < 4; ++r) {
      const int row = quad * 4 + r;
      const float mu = mrow[row * 2], sc = mrow[row * 2 + 1];
      Y[(size_t)(n0 + row) * DMODEL + j] = (vb[s][r] - mu) * sc * gj + bj;
    }
  }
}

// ---------------------------------------------------------------------------
extern "C" void kernel_launch(void* const* d_in, const int* in_sizes, int n_in,
                              void* d_out, int out_size, void* d_ws, size_t ws_size,
                              hipStream_t stream)
{
  const float* Q     = (const float*)d_in[0];
  const float* K     = (const float*)d_in[1];
  const float* V     = (const float*)d_in[2];
  const float* WQ    = (const float*)d_in[3];
  const float* bQ    = (const float*)d_in[4];
  const float* WK    = (const float*)d_in[5];
  const float* bK    = (const float*)d_in[6];
  const float* WV    = (const float*)d_in[7];
  const float* bV    = (const float*)d_in[8];
  const float* WO    = (const float*)d_in[9];
  const float* bO    = (const float*)d_in[10];
  const float* gamma = (const float*)d_in[11];
  const float* beta  = (const float*)d_in[12];

  const size_t MB = 1ull << 20;
  char* ws = (char*)d_ws;
  u16* Qb   = (u16*)(ws + 0 * MB);                  // 4 MB each
  u16* Kb   = (u16*)(ws + 4 * MB);
  u16* Vb   = (u16*)(ws + 8 * MB);
  u16* WQb  = (u16*)(ws + 12 * MB);                 // 0.5 MB each
  u16* WKb  = (u16*)(ws + 12 * MB + 512 * 1024);
  u16* WVb  = (u16*)(ws + 13 * MB);
  u16* WOb  = (u16*)(ws + 13 * MB + 512 * 1024);
  u16* Qs   = (u16*)(ws + 14 * MB);                 // 4 MB each
  u16* Ks   = (u16*)(ws + 18 * MB);
  u16* Vt   = (u16*)(ws + 22 * MB);                 // projected V^T [j][n]
  u16* Opart = (u16*)(ws + 30 * MB);                // 16 MB bf16
  float* Lpart = (float*)(ws + 46 * MB);            // 0.5 MB
  float* out = (float*)d_out;

  cvt7_kernel<<<7168, 256, 0, stream>>>(Q, K, V, WQ, WK, WV, WO,
                                        Qb, Kb, Vb, WQb, WKb, WVb, WOb);
  proj3_kernel<<<dim3(32, 8, 3), 256, 0, stream>>>(Qb, Kb, Vb, WQb, WKb, WVb,
                                                   bQ, bK, bV, Qs, Ks, Vt);
  attn_kernel<<<dim3(32, 16), 512, 0, stream>>>(Qs, Ks, Vt, Opart, Lpart);
  outfuse_kernel<<<256, 1024, 0, stream>>>(Opart, Lpart, WOb, bO, Q,
                                           gamma, beta, out);
}

// Round 11
// 163.124 us; speedup vs baseline: 1.1453x; 1.0136x over previous
//
#include <hip/hip_runtime.h>
#include <cstdint>

#define N_TOK 4096
#define DMODEL 512
#define NHEADS 8
#define HDIM 64

typedef unsigned short u16;
typedef __bf16 bf16x8 __attribute__((ext_vector_type(8)));
typedef float f32x4 __attribute__((ext_vector_type(4)));

union U128 { uint4 u; bf16x8 b; u16 s[8]; };

__device__ __forceinline__ u16 f2bf(float f) {           // RNE
  uint32_t u = __builtin_bit_cast(uint32_t, f);
  u += 0x7FFFu + ((u >> 16) & 1u);
  return (u16)(u >> 16);
}
__device__ __forceinline__ float bf2f(u16 s) {
  uint32_t u = ((uint32_t)s) << 16;
  return __builtin_bit_cast(float, u);
}

#if __has_builtin(__builtin_amdgcn_exp2f)
#define EXP2(x) __builtin_amdgcn_exp2f(x)
#else
#define EXP2(x) __expf((x) * 0.6931471805599453f)
#endif

// v_cvt_pk_bf16_f32: packs two f32 into one u32 of 2 bf16 (RNE), src0 -> lo.
__device__ __forceinline__ uint32_t cvtpk(float lo, float hi) {
  uint32_t r;
  asm("v_cvt_pk_bf16_f32 %0, %1, %2" : "=v"(r) : "v"(lo), "v"(hi));
  return r;
}

// async global->LDS, 16B/lane, dest = wave-uniform base + lane*16
__device__ __forceinline__ void ldg2lds16(const void* g, void* s) {
  __builtin_amdgcn_global_load_lds(
      (const __attribute__((address_space(1))) void*)g,
      (__attribute__((address_space(3))) void*)s, 16, 0, 0);
}

// ---------------------------------------------------------------------------
// Kernel 0: fp32 -> bf16 pre-convert of Q,K,V,WQ,WK,WV,WO.  7168 x 256.
// (r19 lesson: conversion lives in coalesced streaming passes; staging bf16.)
// ---------------------------------------------------------------------------
__global__ __launch_bounds__(256) void cvt7_kernel(
    const float* __restrict__ Q, const float* __restrict__ K, const float* __restrict__ V,
    const float* __restrict__ WQ, const float* __restrict__ WK, const float* __restrict__ WV,
    const float* __restrict__ WO,
    u16* __restrict__ Qb, u16* __restrict__ Kb, u16* __restrict__ Vb,
    u16* __restrict__ WQb, u16* __restrict__ WKb, u16* __restrict__ WVb,
    u16* __restrict__ WOb)
{
  int b = blockIdx.x;
  const float* src; u16* dst; int rel;
  if      (b < 2048) { src = Q;  dst = Qb;  rel = b; }
  else if (b < 4096) { src = K;  dst = Kb;  rel = b - 2048; }
  else if (b < 6144) { src = V;  dst = Vb;  rel = b - 4096; }
  else if (b < 6400) { src = WQ; dst = WQb; rel = b - 6144; }
  else if (b < 6656) { src = WK; dst = WKb; rel = b - 6400; }
  else if (b < 6912) { src = WV; dst = WVb; rel = b - 6656; }
  else               { src = WO; dst = WOb; rel = b - 6912; }
  int i = (rel * 256 + threadIdx.x) * 4;
  float4 f = *(const float4*)(src + i);
  ushort4 o;
  o.x = f2bf(f.x); o.y = f2bf(f.y); o.z = f2bf(f.z); o.w = f2bf(f.w);
  *(ushort4*)(dst + i) = o;
}

// ---------------------------------------------------------------------------
// Kernel 1 (r20, verified): fused QKV projection with COALESCED staging
// (8 consecutive rows x 128B per global_load_lds, rule-21c swizzle).
// 128x64 tile, m=2, double-buffered.  grid (32, 8, 3), block 256.
// ---------------------------------------------------------------------------
__global__ __launch_bounds__(256) void proj3_kernel(
    const u16* __restrict__ Qb, const u16* __restrict__ Kb, const u16* __restrict__ Vb,
    const u16* __restrict__ WQb, const u16* __restrict__ WKb, const u16* __restrict__ WVb,
    const float* __restrict__ bQ, const float* __restrict__ bK, const float* __restrict__ bV,
    u16* __restrict__ Qs, u16* __restrict__ Ks, u16* __restrict__ Vt)
{
  const int z = blockIdx.z;
  const u16* A      = (z == 0) ? Qb : (z == 1) ? Kb : Vb;
  const u16* W      = (z == 0) ? WQb : (z == 1) ? WKb : WVb;
  const float* bias = (z == 0) ? bQ : (z == 1) ? bK : bV;

  const int m0 = blockIdx.x * 128;
  const int j0 = blockIdx.y * 64;
  const int tid = threadIdx.x;
  const int w = tid >> 6, lane = tid & 63, quad = lane >> 4, l = lane & 15;

  __shared__ bf16x8 sA[2][128 * 8];  // [row][slot] 32 KB
  __shared__ bf16x8 sB[2][64 * 8];   // [row][slot] 16 KB

  const f32x4 zero = {0.f, 0.f, 0.f, 0.f};
  f32x4 acc[2][4];
#pragma unroll
  for (int m = 0; m < 2; ++m)
#pragma unroll
    for (int s = 0; s < 4; ++s) acc[m][s] = zero;

  const int rsub = lane >> 3;            // 0..7: row within 8-row group
  const int gchunk = (lane & 7) ^ rsub;  // pre-swizzled source k-chunk

  auto stage = [&](int kt, int buf) {
    const int k0 = kt * 64;
#pragma unroll
    for (int t = 0; t < 4; ++t) {
      const int row = w * 32 + t * 8;
      const u16* ag = A + (size_t)(m0 + row + rsub) * DMODEL + k0 + gchunk * 8;
      ldg2lds16(ag, (char*)&sA[buf][row * 8]);
    }
#pragma unroll
    for (int i = 0; i < 2; ++i) {
      const int row = w * 16 + i * 8;
      const u16* bg = W + (size_t)(j0 + row + rsub) * DMODEL + k0 + gchunk * 8;
      ldg2lds16(bg, (char*)&sB[buf][row * 8]);
    }
  };

  stage(0, 0);
  __syncthreads();
  for (int kt = 0; kt < 8; ++kt) {
    const int buf = kt & 1;
    if (kt + 1 < 8) stage(kt + 1, buf ^ 1);
#pragma unroll
    for (int c = 0; c < 2; ++c) {
      const int sl = (c * 4 + quad) ^ (l & 7);   // swizzled read slot
      bf16x8 af0 = sA[buf][(w * 32 + l) * 8 + sl];
      bf16x8 af1 = sA[buf][(w * 32 + 16 + l) * 8 + sl];
#pragma unroll
      for (int s = 0; s < 4; ++s) {
        bf16x8 bfb = sB[buf][(s * 16 + l) * 8 + sl];
        acc[0][s] = __builtin_amdgcn_mfma_f32_16x16x32_bf16(af0, bfb, acc[0][s], 0, 0, 0);
        acc[1][s] = __builtin_amdgcn_mfma_f32_16x16x32_bf16(af1, bfb, acc[1][s], 0, 0, 0);
      }
    }
    __syncthreads();
  }

#pragma unroll
  for (int m = 0; m < 2; ++m)
#pragma unroll
    for (int s = 0; s < 4; ++s) {
      int j = j0 + s * 16 + l;
      float bv = bias[j];
      int n0 = m0 + w * 32 + m * 16 + quad * 4;
      if (z < 2) {
        u16* Y = (z == 0) ? Qs : Ks;
#pragma unroll
        for (int r = 0; r < 4; ++r)
          Y[(size_t)(n0 + r) * DMODEL + j] = f2bf(acc[m][s][r] + bv);
      } else {
        ushort4 pk;
        pk.x = f2bf(acc[m][s][0] + bv); pk.y = f2bf(acc[m][s][1] + bv);
        pk.z = f2bf(acc[m][s][2] + bv); pk.w = f2bf(acc[m][s][3] + bv);
        *(ushort4*)(Vt + (size_t)j * N_TOK + n0) = pk;   // V^T write
      }
    }
}

// ---------------------------------------------------------------------------
// Kernel 2 (r21): flash attention — r16 config with COALESCED K/V staging.
// Old stage() was lane->row scattered (64x16B txns/inst at 1KB / 8KB
// strides).  New: row-major LDS [key][slot] / [vd][slot]; each
// global_load_lds covers 8 consecutive rows x 128B = 8 coalesced txns
// (8x less TA pressure) — the exact transform that won r20, bit-identical
// by the same derivation (rows≡0 mod 8 -> row&7 = rsub; fragment rows
// t*16+l / s*16+l have &7 == l&7 -> writer/reader swizzle keys agree).
// pbuf swizzle, geometry, VALU diet all FROZEN.  absmax probe: 0.03125.
// ---------------------------------------------------------------------------
__global__ __launch_bounds__(512, 4) void attn_kernel(
    const u16* __restrict__ Qs, const u16* __restrict__ Ks,
    const u16* __restrict__ Vt, u16* __restrict__ Opart, float* __restrict__ Lpart)
{
  const int hs = blockIdx.x;                 // h + 8*split
  const int h = hs & 7, split = hs >> 3;
  const int qt = blockIdx.y;
  const int tid = threadIdx.x;
  const int w = tid >> 6, lane = tid & 63, quad = lane >> 4, l = lane & 15;

  __shared__ bf16x8 kch[2][64 * 8];                // 16 KB  [key][slot]
  __shared__ bf16x8 vch[2][64 * 8];                // 16 KB  [vd][slot]
  __shared__ __align__(128) u16 pbuf[8][32][64];   // 32 KB  [wave][q][128B swizzled row]

  const int wq0 = qt * 256 + w * 32;

  // Q fragments (B-operand), pre-scaled by log2(e)/8
  bf16x8 qf[2][2];
#pragma unroll
  for (int c = 0; c < 2; ++c)
#pragma unroll
    for (int m = 0; m < 2; ++m) {
      U128 u;
      u.u = *(const uint4*)(Qs + (size_t)(wq0 + m * 16 + l) * DMODEL + h * HDIM + c * 32 + quad * 8);
#pragma unroll
      for (int j = 0; j < 8; ++j) u.s[j] = f2bf(bf2f(u.s[j]) * 0.18033688f);
      qf[c][m] = u.b;
    }

  // all-ones B-fragment for the lsum MFMA (bf16 1.0 = 0x3F80)
  U128 onesu;
#pragma unroll
  for (int j = 0; j < 8; ++j) onesu.s[j] = 0x3F80;

  const f32x4 zero = {0.f, 0.f, 0.f, 0.f};
  f32x4 o[2][4];
  f32x4 ol[2];               // lsum accumulators: ol[m][r] = lsum[q=m*16+quad*4+r]
  ol[0] = zero; ol[1] = zero;
#pragma unroll
  for (int m = 0; m < 2; ++m)
#pragma unroll
    for (int s = 0; s < 4; ++s) o[m][s] = zero;

  const int rsub = lane >> 3;            // row within 8-row group
  const int gch  = (lane & 7) ^ rsub;    // pre-swizzled source chunk

  auto stage = [&](int it, int buf) {
    const int j0 = split * 1024 + it * 64;
    if (w < 4) {            // waves 0-3 stage K rows w*16..w*16+15
#pragma unroll
      for (int t = 0; t < 2; ++t) {
        const int row = w * 16 + t * 8;
        const u16* kg = Ks + (size_t)(j0 + row + rsub) * DMODEL + h * HDIM + gch * 8;
        ldg2lds16(kg, (char*)&kch[buf][row * 8]);
      }
    } else {                // waves 4-7 stage V^T rows (vd) w2*16..+15
      const int w2 = w - 4;
#pragma unroll
      for (int t = 0; t < 2; ++t) {
        const int row = w2 * 16 + t * 8;
        const u16* vg = Vt + (size_t)(h * HDIM + row + rsub) * N_TOK + j0 + gch * 8;
        ldg2lds16(vg, (char*)&vch[buf][row * 8]);
      }
    }
  };

  stage(0, 0);
  __syncthreads();

  const unsigned swz = (unsigned)((l & 7) << 4);   // pbuf per-row XOR (row&7 == l&7)

  for (int it = 0; it < 16; ++it) {
    const int buf = it & 1;
    if (it + 1 < 16) stage(it + 1, buf ^ 1);   // prefetch overlaps compute

#pragma unroll
    for (int kh = 0; kh < 2; ++kh) {           // two 32-key halves
#pragma unroll
      for (int tt = 0; tt < 2; ++tt) {
        const int t = kh * 2 + tt;
        f32x4 sacc[2];
        sacc[0] = zero; sacc[1] = zero;
#pragma unroll
        for (int c = 0; c < 2; ++c) {
          bf16x8 kf = kch[buf][(t * 16 + l) * 8 + ((c * 4 + quad) ^ (l & 7))];
          sacc[0] = __builtin_amdgcn_mfma_f32_16x16x32_bf16(kf, qf[c][0], sacc[0], 0, 0, 0);
          sacc[1] = __builtin_amdgcn_mfma_f32_16x16x32_bf16(kf, qf[c][1], sacc[1], 0, 0, 0);
        }
#pragma unroll
        for (int m = 0; m < 2; ++m) {
          uint2 st;
          st.x = cvtpk(EXP2(sacc[m][0]), EXP2(sacc[m][1]));
          st.y = cvtpk(EXP2(sacc[m][2]), EXP2(sacc[m][3]));
          char* pb = (char*)&pbuf[w][m * 16 + l][0];
          *(uint2*)(pb + (((unsigned)(tt * 32 + quad * 8)) ^ swz)) = st;
        }
      }
      // PV for this key half (contraction = 32 keys, quad covers them)
      U128 pf0, pf1;
      const unsigned ro = ((unsigned)(quad * 16)) ^ swz;
      pf0.u = *(const uint4*)((const char*)&pbuf[w][l][0] + ro);
      pf1.u = *(const uint4*)((const char*)&pbuf[w][16 + l][0] + ro);
#pragma unroll
      for (int s = 0; s < 4; ++s) {
        bf16x8 vf = vch[buf][(s * 16 + l) * 8 + ((kh * 4 + quad) ^ (l & 7))];
        o[0][s] = __builtin_amdgcn_mfma_f32_16x16x32_bf16(pf0.b, vf, o[0][s], 0, 0, 0);
        o[1][s] = __builtin_amdgcn_mfma_f32_16x16x32_bf16(pf1.b, vf, o[1][s], 0, 0, 0);
      }
      // lsum = P . 1 on the matrix pipe
      ol[0] = __builtin_amdgcn_mfma_f32_16x16x32_bf16(pf0.b, onesu.b, ol[0], 0, 0, 0);
      ol[1] = __builtin_amdgcn_mfma_f32_16x16x32_bf16(pf1.b, onesu.b, ol[1], 0, 0, 0);
    }
    __syncthreads();   // publishes next buf's loads; orders buf reuse
  }

  // ol[m][r] holds lsum for q = m*16+quad*4+r, replicated across l=0..15.
  if (l == 0) {
    float* Lp = Lpart + ((size_t)split * NHEADS + h) * N_TOK + wq0;
#pragma unroll
    for (int m = 0; m < 2; ++m)
#pragma unroll
      for (int r = 0; r < 4; ++r)
        Lp[m * 16 + quad * 4 + r] = ol[m][r];
  }
  // Opart[split][h][q][vd] bf16 (unnormalized)
  u16* Ob = Opart + ((size_t)(split * NHEADS + h) * N_TOK + wq0) * 64;
#pragma unroll
  for (int m = 0; m < 2; ++m)
#pragma unroll
    for (int s = 0; s < 4; ++s)
#pragma unroll
      for (int r = 0; r < 4; ++r)
        Ob[(size_t)(m * 16 + quad * 4 + r) * 64 + s * 16 + l] = f2bf(o[m][s][r]);
}

// ---------------------------------------------------------------------------
// Kernel 3: fused combine + output-GEMM + LayerNorm (r18 verified version).
// grid 256 x 1024 thr (16 waves), block owns 16 token rows.
// ---------------------------------------------------------------------------
__global__ __launch_bounds__(1024) void outfuse_kernel(
    const u16* __restrict__ Opart, const float* __restrict__ Lpart,
    const u16* __restrict__ WOb, const float* __restrict__ bO,
    const float* __restrict__ resid, const float* __restrict__ gamma,
    const float* __restrict__ beta, float* __restrict__ Y)
{
  __shared__ __align__(128) char smem[16384 + 2 * 65536];   // 144 KB
  bf16x8* sA = (bf16x8*)smem;                 // [64 col8][16 n]   (16 KB)
  bf16x8* sB = (bf16x8*)(smem + 16384);       // [2][512 j][8 ch'] (2x64 KB)
  float* pls = (float*)smem;                  // reused after GEMM: [16 row][16 wave]
  float* plq = (float*)smem + 256;
  float* mrow = (float*)smem + 512;           // [16][2] mu, inv-sigma

  const int tid = threadIdx.x;
  const int w = tid >> 6, lane = tid & 63, quad = lane >> 4, l = lane & 15;
  const int n0 = blockIdx.x * 16;

  auto stageB = [&](int kt, int buf) {
#pragma unroll
    for (int t = 0; t < 4; ++t) {
      const int jb = w * 32 + t * 8;
      const u16* g = WOb + (size_t)(jb + (lane >> 3)) * DMODEL + kt * 64
                   + (((lane & 7) ^ (lane >> 3)) * 8);
      ldg2lds16(g, (char*)&sB[(size_t)buf * 4096 + jb * 8]);
    }
  };

  stageB(0, 0);

  // ---- phase 1: combine -> sA (ctx tile [16 rows][512 cols] as [col8][n])
  {
    const int h = tid >> 7;
    const int n = (tid >> 3) & 15;
    const int vd0 = (tid & 7) * 8;
    float a8[8] = {0, 0, 0, 0, 0, 0, 0, 0};
    float lsum = 0.f;
#pragma unroll
    for (int s = 0; s < 4; ++s) {
      U128 u;
      u.u = *(const uint4*)(Opart + ((size_t)(s * NHEADS + h) * N_TOK + n0 + n) * 64 + vd0);
#pragma unroll
      for (int j = 0; j < 8; ++j) a8[j] += bf2f(u.s[j]);
      lsum += Lpart[((size_t)s * NHEADS + h) * N_TOK + n0 + n];
    }
    float inv = 1.f / lsum;
    U128 o;
#pragma unroll
    for (int j = 0; j < 8; ++j) o.s[j] = f2bf(a8[j] * inv);
    const int col8 = h * 8 + (tid & 7);
    *(uint4*)&sA[col8 * 16 + n] = o.u;
  }
  __syncthreads();

  // ---- phase 2: GEMM out[16][512] = ctx . WOb^T, wave w -> j in [w*32, w*32+32)
  const f32x4 zero = {0.f, 0.f, 0.f, 0.f};
  f32x4 acc[2];
  acc[0] = zero; acc[1] = zero;

  for (int kt = 0; kt < 8; ++kt) {
    const int buf = kt & 1;
    if (kt + 1 < 8) stageB(kt + 1, buf ^ 1);
#pragma unroll
    for (int c = 0; c < 2; ++c) {
      bf16x8 af = sA[(kt * 8 + c * 4 + quad) * 16 + l];
#pragma unroll
      for (int s = 0; s < 2; ++s) {
        const int j = w * 32 + s * 16 + l;
        bf16x8 bfb = sB[(size_t)buf * 4096 + j * 8 + ((c * 4 + quad) ^ (l & 7))];
        acc[s] = __builtin_amdgcn_mfma_f32_16x16x32_bf16(af, bfb, acc[s], 0, 0, 0);
      }
    }
    __syncthreads();
  }

  // ---- phase 3: bias + residual, LN, write
  float vb[2][4];
#pragma unroll
  for (int s = 0; s < 2; ++s) {
    const int j = w * 32 + s * 16 + l;
    const float bv = bO[j];
#pragma unroll
    for (int r = 0; r < 4; ++r)
      vb[s][r] = acc[s][r] + bv + resid[(size_t)(n0 + quad * 4 + r) * DMODEL + j];
  }
#pragma unroll
  for (int r = 0; r < 4; ++r) {
    float sm = vb[0][r] + vb[1][r];
    float sq = vb[0][r] * vb[0][r] + vb[1][r] * vb[1][r];
#pragma unroll
    for (int mk = 1; mk < 16; mk <<= 1) {
      sm += __shfl_xor(sm, mk);
      sq += __shfl_xor(sq, mk);
    }
    if (l == 0) {
      pls[(quad * 4 + r) * 16 + w] = sm;
      plq[(quad * 4 + r) * 16 + w] = sq;
    }
  }
  __syncthreads();
  if (tid < 16) {
    float sm = 0.f, sq = 0.f;
#pragma unroll
    for (int w2 = 0; w2 < 16; ++w2) { sm += pls[tid * 16 + w2]; sq += plq[tid * 16 + w2]; }
    const float mu = sm * (1.f / DMODEL);
    const float var = sq * (1.f / DMODEL) - mu * mu;
    mrow[tid * 2]     = mu;
    mrow[tid * 2 + 1] = rsqrtf(var + 1e-5f);
  }
  __syncthreads();
#pragma unroll
  for (int s = 0; s < 2; ++s) {
    const int j = w * 32 + s * 16 + l;
    const float gj = gamma[j], bj = beta[j];
#pragma unroll
    for (int r = 0; r < 4; ++r) {
      const int row = quad * 4 + r;
      const float mu = mrow[row * 2], sc = mrow[row * 2 + 1];
      Y[(size_t)(n0 + row) * DMODEL + j] = (vb[s][r] - mu) * sc * gj + bj;
    }
  }
}

// ---------------------------------------------------------------------------
extern "C" void kernel_launch(void* const* d_in, const int* in_sizes, int n_in,
                              void* d_out, int out_size, void* d_ws, size_t ws_size,
                              hipStream_t stream)
{
  const float* Q     = (const float*)d_in[0];
  const float* K     = (const float*)d_in[1];
  const float* V     = (const float*)d_in[2];
  const float* WQ    = (const float*)d_in[3];
  const float* bQ    = (const float*)d_in[4];
  const float* WK    = (const float*)d_in[5];
  const float* bK    = (const float*)d_in[6];
  const float* WV    = (const float*)d_in[7];
  const float* bV    = (const float*)d_in[8];
  const float* WO    = (const float*)d_in[9];
  const float* bO    = (const float*)d_in[10];
  const float* gamma = (const float*)d_in[11];
  const float* beta  = (const float*)d_in[12];

  const size_t MB = 1ull << 20;
  char* ws = (char*)d_ws;
  u16* Qb   = (u16*)(ws + 0 * MB);                  // 4 MB each
  u16* Kb   = (u16*)(ws + 4 * MB);
  u16* Vb   = (u16*)(ws + 8 * MB);
  u16* WQb  = (u16*)(ws + 12 * MB);                 // 0.5 MB each
  u16* WKb  = (u16*)(ws + 12 * MB + 512 * 1024);
  u16* WVb  = (u16*)(ws + 13 * MB);
  u16* WOb  = (u16*)(ws + 13 * MB + 512 * 1024);
  u16* Qs   = (u16*)(ws + 14 * MB);                 // 4 MB each
  u16* Ks   = (u16*)(ws + 18 * MB);
  u16* Vt   = (u16*)(ws + 22 * MB);                 // projected V^T [j][n]
  u16* Opart = (u16*)(ws + 30 * MB);                // 16 MB bf16
  float* Lpart = (float*)(ws + 46 * MB);            // 0.5 MB
  float* out = (float*)d_out;

  cvt7_kernel<<<7168, 256, 0, stream>>>(Q, K, V, WQ, WK, WV, WO,
                                        Qb, Kb, Vb, WQb, WKb, WVb, WOb);
  proj3_kernel<<<dim3(32, 8, 3), 256, 0, stream>>>(Qb, Kb, Vb, WQb, WKb, WVb,
                                                   bQ, bK, bV, Qs, Ks, Vt);
  attn_kernel<<<dim3(32, 16), 512, 0, stream>>>(Qs, Ks, Vt, Opart, Lpart);
  outfuse_kernel<<<256, 1024, 0, stream>>>(Opart, Lpart, WOb, bO, Q,
                                           gamma, beta, out);
}